// Round 3
// baseline (239.591 us; speedup 1.0000x reference)
//
#include <hip/hip_runtime.h>
#include <hip/hip_bf16.h>
#include <math.h>

// Tucker MoE: T=1024, D=1024, DFF=1024, R=64, G=8, E=32, NEXP=256, K=8, F=8192
// Round 12: dispatch-chain reduction (overhead hypothesis test).
//  - router+topk moved INTO D2 as 128 extra blocks (b<128, dispatched first):
//    full-D fp32 dot from LDS-staged x, topk from LDS logits. lp buffer and
//    its 8 MB round trip deleted.
//  - 256-entry scan folded into D2 tail: last router block (ticket) scans
//    cnt (coherent atomic reads) -> off. k_scan dispatch deleted.
//  - chain L1->L2->L3 (3 launches) becomes L1->L2 (2 launches).
// 6 dispatches:
//  D1 k_prep       : casts/transposes + cnt/tickets/Y zero
//  D2 k_pre_router : router+topk+scan (128 blk) || pre MFMA (512 blk)
//  D3 k_core_gu    : per-expert gate/up core (LDS, fp32) -> xgb/xub[p]
//  D4 k_fused_ad   : act(gate/up MFMA + silu*mul in LDS) fused w/ down MFMA
//  D5 k_down_core  : per-expert fold xdp + down core + wsm -> atomic Y fp32
//  D6 k_fin        : dense out = Y[1024,512] @ Uod2[512,1024] (bf16 MFMA)

#define T_ 1024
#define D_ 1024
#define DFF_ 1024
#define R_ 64
#define G_ 8
#define E_ 32
#define NEXP_ 256
#define K_ 8
#define F_ 8192
#define PKZ_ 2   // k_pre split-K
#define DKZ_ 4   // down split-K (chunks of 256 over DFF)
#define LP_ 72   // LDS tile pitch in bf16 elems (16B rows, 2-way bank alias = free)

typedef short bf16x8 __attribute__((ext_vector_type(8)));
typedef float f32x4 __attribute__((ext_vector_type(4)));

__device__ __forceinline__ unsigned short f2bf(float f) {
  unsigned int u = __float_as_uint(f);
  u += 0x7fffu + ((u >> 16) & 1u);  // RNE (finite inputs)
  return (unsigned short)(u >> 16);
}

__device__ __forceinline__ void stage_tile(short* dst, const unsigned short* src,
                                           int gp, int tid) {
  for (int idx = tid; idx < 512; idx += 256) {
    int r = idx >> 3, c8 = (idx & 7) << 3;
    *(uint4*)&dst[r * LP_ + c8] = *(const uint4*)&src[(size_t)r * gp + c8];
  }
}

__device__ __forceinline__ void stage_tile_guard(short* dst, const unsigned short* src,
                                                 int gp, int rows_valid, int tid) {
  for (int idx = tid; idx < 512; idx += 256) {
    int r = idx >> 3, c8 = (idx & 7) << 3;
    uint4 v = make_uint4(0u, 0u, 0u, 0u);
    if (r < rows_valid) v = *(const uint4*)&src[(size_t)r * gp + c8];
    *(uint4*)&dst[r * LP_ + c8] = v;
  }
}

// Stage a 64x64 bf16 tile from an fp32 source (convert on the fly).
__device__ __forceinline__ void stage_tile_f32(short* dst, const float* src,
                                               int gp, int tid) {
  for (int idx = tid; idx < 512; idx += 256) {
    int r = idx >> 3, c8 = (idx & 7) << 3;
    const float* s = &src[(size_t)r * gp + c8];
    float4 v0 = *(const float4*)s;
    float4 v1 = *(const float4*)(s + 4);
    uint4 u;
    u.x = ((unsigned)f2bf(v0.y) << 16) | f2bf(v0.x);
    u.y = ((unsigned)f2bf(v0.w) << 16) | f2bf(v0.z);
    u.z = ((unsigned)f2bf(v1.y) << 16) | f2bf(v1.x);
    u.w = ((unsigned)f2bf(v1.w) << 16) | f2bf(v1.z);
    *(uint4*)&dst[r * LP_ + c8] = u;
  }
}

// Wave computes a 16x64 strip (rows [ms,ms+16)) over K=64 from LDS tiles
// As (rows=m, k-contig) and Bs (rows=n, k-contig; i.e. B^T).
__device__ __forceinline__ void mma_strip(const short* As, const short* Bs,
                                          int ms, int lane, f32x4* acc) {
  int lm = lane & 15;
  int lk = (lane >> 4) << 3;
#pragma unroll
  for (int kc = 0; kc < 64; kc += 32) {
    bf16x8 a = *(const bf16x8*)&As[(ms + lm) * LP_ + kc + lk];
#pragma unroll
    for (int nt = 0; nt < 4; ++nt) {
      bf16x8 b = *(const bf16x8*)&Bs[(nt * 16 + lm) * LP_ + kc + lk];
      acc[nt] = __builtin_amdgcn_mfma_f32_16x16x32_bf16(a, b, acc[nt], 0, 0, 0);
    }
  }
}

// ---------------------------------------------------------------- D1: prep
// 896 blocks: id=b>>7: 0..4 cast+T, id 5 = uout_down -> Uod2T[d][g*64+r],
// id 6 = x cast + cnt/tickets zero + Y zero.
__global__ __launch_bounds__(256) void k_prep(
    const float* __restrict__ x,
    const float* __restrict__ s0, const float* __restrict__ s1,
    const float* __restrict__ s2, const float* __restrict__ s3,
    const float* __restrict__ s4, const float* __restrict__ s5,
    unsigned short* __restrict__ xb,
    unsigned short* __restrict__ d0, unsigned short* __restrict__ d1,
    unsigned short* __restrict__ d2, unsigned short* __restrict__ d3,
    unsigned short* __restrict__ d4, unsigned short* __restrict__ d5,
    int* __restrict__ cnt, int* __restrict__ tickets, float* __restrict__ Yf) {
  __shared__ float shbuf[64 * 65];
  int b = blockIdx.x;
  int id = b >> 7, rem = b & 127, g = rem >> 4, tile = rem & 15;
  if (id == 6) {
    size_t base = ((size_t)g * 16 + tile) * 8192;
    for (int i = threadIdx.x; i < 2048; i += 256) {
      size_t idx = base + (size_t)i * 4;
      float4 v = *(const float4*)&x[idx];
      xb[idx + 0] = f2bf(v.x);
      xb[idx + 1] = f2bf(v.y);
      xb[idx + 2] = f2bf(v.z);
      xb[idx + 3] = f2bf(v.w);
    }
    // zero Y: 128 blocks x 4096 floats = 1024x512
    size_t ybase = ((size_t)g * 16 + tile) * 4096;
    float4 z4 = make_float4(0.f, 0.f, 0.f, 0.f);
    for (int i = threadIdx.x; i < 1024; i += 256)
      *(float4*)&Yf[ybase + (size_t)i * 4] = z4;
    if (g == 0 && tile == 0) {
      cnt[threadIdx.x] = 0;
      if (threadIdx.x == 0) tickets[0] = 0;
    }
    return;
  }
  const float* src = id == 0 ? s0 : id == 1 ? s1 : id == 2 ? s2 : id == 3 ? s3 : id == 4 ? s4 : s5;
  unsigned short* dst = id == 0 ? d0 : id == 1 ? d1 : id == 2 ? d2 : id == 3 ? d3 : id == 4 ? d4 : d5;
  if (id < 3) {
    // uin*: src [g][1024][64] -> dst [g][64][1024]
    int r0 = tile * 64;
    for (int idx = threadIdx.x; idx < 4096; idx += 256) {
      int r = idx >> 6, c = idx & 63;
      shbuf[r * 65 + c] = src[((size_t)g * 1024 + r0 + r) * 64 + c];
    }
    __syncthreads();
    for (int idx = threadIdx.x; idx < 4096; idx += 256) {
      int c = idx >> 6, r = idx & 63;
      dst[((size_t)g * 64 + c) * 1024 + r0 + r] = f2bf(shbuf[r * 65 + c]);
    }
  } else {
    // uout*: src [g][64][1024]; id 3/4 -> [g][1024][64]; id 5 -> [d][g*64+r]
    int c0 = tile * 64;
    for (int idx = threadIdx.x; idx < 4096; idx += 256) {
      int r = idx >> 6, c = idx & 63;
      shbuf[r * 65 + c] = src[((size_t)g * 64 + r) * 1024 + c0 + c];
    }
    __syncthreads();
    if (id == 5) {
      for (int idx = threadIdx.x; idx < 4096; idx += 256) {
        int c = idx >> 6, r = idx & 63;
        dst[(size_t)(c0 + c) * 512 + g * 64 + r] = f2bf(shbuf[r * 65 + c]);
      }
    } else {
      for (int idx = threadIdx.x; idx < 4096; idx += 256) {
        int c = idx >> 6, r = idx & 63;
        dst[((size_t)g * 1024 + c0 + c) * 64 + r] = f2bf(shbuf[r * 65 + c]);
      }
    }
  }
}

// ---------------------------------------------------------------- D2: router+topk+scan || pre MFMA
// Grid 640: b<128 = router blocks (8 tokens each; full-D fp32 logits from
// LDS-staged x, topk, bucket/cnt atomics; LAST router block scans cnt->off).
// b>=128 = 512 pre-MFMA blocks (b2=b-128, same as r11's k_pre part).
__global__ __launch_bounds__(256) void k_pre_router(
    const float* __restrict__ x, const float* __restrict__ Wg,
    const unsigned short* __restrict__ xb,
    const unsigned short* __restrict__ uinT_g, const unsigned short* __restrict__ uinT_u,
    float* __restrict__ Pgp, float* __restrict__ Pup,
    float* __restrict__ wsm, int* __restrict__ bucket, int* __restrict__ cnt,
    int* __restrict__ tickets, int* __restrict__ off) {
  __shared__ float smf[8192];  // 32 KB union: xs[8][1024] / lg[8][256] / MFMA tiles / scan
  __shared__ int lastfl;
  int b = blockIdx.x;
  int tid = threadIdx.x;
  if (b >= 128) {
    int b2 = b - 128;
    int tile = b2 & 15, g = (b2 >> 4) & 7, zz = b2 >> 7;
    int gu = zz >> 1, kz = zz & 1;
    const unsigned short* U = gu ? uinT_u : uinT_g;  // [G][64(r)][1024(d)]
    float* P = gu ? Pup : Pgp;
    int t0 = tile * 64;
    short* As = (short*)smf;
    short* Bs = (short*)smf + 64 * LP_;
    int lane = tid & 63, ms = (tid >> 6) * 16;
    f32x4 acc[4] = {};
    int dlo = kz * (D_ / PKZ_);
    for (int dc = dlo; dc < dlo + D_ / PKZ_; dc += 64) {
      stage_tile(As, xb + (size_t)t0 * D_ + dc, D_, tid);
      stage_tile(Bs, U + (size_t)g * 64 * 1024 + dc, 1024, tid);
      __syncthreads();
      mma_strip(As, Bs, ms, lane, acc);
      __syncthreads();
    }
    int lm = lane & 15, lq = (lane >> 4) * 4;
#pragma unroll
    for (int nt = 0; nt < 4; ++nt)
#pragma unroll
      for (int r = 0; r < 4; ++r)
        P[((size_t)(kz * G_ + g) * T_ + t0 + ms + lq + r) * R_ + nt * 16 + lm] = acc[nt][r];
    return;
  }
  // ---- router: 8 tokens, thread = expert
  int t0 = b * 8;
  for (int i = tid; i < 2048; i += 256) {
    int j = i >> 8, d4 = (i & 255) << 2;
    *(float4*)&smf[j * 1024 + d4] = *(const float4*)&x[(size_t)(t0 + j) * D_ + d4];
  }
  __syncthreads();
  int e = tid;
  float a[8] = {};
#pragma unroll 2
  for (int d2 = 0; d2 < 1024; d2 += 4) {
    float w0 = Wg[(size_t)(d2 + 0) * NEXP_ + e];
    float w1 = Wg[(size_t)(d2 + 1) * NEXP_ + e];
    float w2 = Wg[(size_t)(d2 + 2) * NEXP_ + e];
    float w3 = Wg[(size_t)(d2 + 3) * NEXP_ + e];
#pragma unroll
    for (int j = 0; j < 8; ++j) {
      float4 xv = *(const float4*)&smf[j * 1024 + d2];  // broadcast ds_read_b128
      float aj = a[j];
      aj = fmaf(xv.x, w0, aj);
      aj = fmaf(xv.y, w1, aj);
      aj = fmaf(xv.z, w2, aj);
      aj = fmaf(xv.w, w3, aj);
      a[j] = aj;
    }
  }
  __syncthreads();  // xs reads complete before alias overwrite
  float* lg = smf;  // [8][256]
#pragma unroll
  for (int j = 0; j < 8; ++j) lg[j * 256 + e] = a[j];
  __syncthreads();
  // ---- topk: wave w handles tokens w*2, w*2+1
  int wave = tid >> 6, lane = tid & 63;
  for (int kk = 0; kk < 2; ++kk) {
    int j = wave * 2 + kk;
    int t = t0 + j;
    float v[4];
    int idx[4];
#pragma unroll
    for (int j2 = 0; j2 < 4; ++j2) {
      idx[j2] = lane + 64 * j2;
      v[j2] = lg[j * 256 + idx[j2]];
    }
    float topv[K_];
    int topi[K_];
#pragma unroll
    for (int k = 0; k < K_; ++k) {
      float bv = v[0];
      int bi = idx[0];
#pragma unroll
      for (int j2 = 1; j2 < 4; ++j2)
        if (v[j2] > bv || (v[j2] == bv && idx[j2] < bi)) { bv = v[j2]; bi = idx[j2]; }
#pragma unroll
      for (int o2 = 32; o2 > 0; o2 >>= 1) {
        float ov = __shfl_xor(bv, o2);
        int oi = __shfl_xor(bi, o2);
        if (ov > bv || (ov == bv && oi < bi)) { bv = ov; bi = oi; }
      }
      topv[k] = bv;
      topi[k] = bi;
#pragma unroll
      for (int j2 = 0; j2 < 4; ++j2)
        if (idx[j2] == bi) v[j2] = -INFINITY;
    }
    float m = topv[0];
    float ev[K_];
    float s = 0.f;
#pragma unroll
    for (int k = 0; k < K_; ++k) { ev[k] = expf(topv[k] - m); s += ev[k]; }
    float inv = 1.f / s;
    if (lane < K_) {
      wsm[t * K_ + lane] = ev[lane] * inv;
      int r1 = atomicAdd(&cnt[topi[lane]], 1);
      bucket[topi[lane] * 1024 + r1] = t * K_ + lane;
    }
  }
  // ---- last router block scans cnt -> off
  __threadfence();
  __syncthreads();
  if (tid == 0) lastfl = (atomicAdd(&tickets[0], 1) == 127) ? 1 : 0;
  __syncthreads();
  if (lastfl) {
    int* s = (int*)smf;
    int i = tid;
    int c0 = atomicAdd(&cnt[i], 0);  // coherent read of final counts
    s[i] = c0;
    __syncthreads();
    for (int d = 1; d < NEXP_; d <<= 1) {
      int vv = (i >= d) ? s[i - d] : 0;
      __syncthreads();
      s[i] += vv;
      __syncthreads();
    }
    off[i + 1] = s[i];
    if (i == 0) off[0] = 0;
  }
}

// ---------------------------------------------------------------- D3: per-expert gate/up core -> xgb/xub[p]
__global__ __launch_bounds__(256) void k_core_gu(const float* __restrict__ Pgp,
                                                 const float* __restrict__ Pup,
                                                 const float* __restrict__ core_g,
                                                 const float* __restrict__ core_u,
                                                 const int* __restrict__ bucket,
                                                 const int* __restrict__ off,
                                                 unsigned short* __restrict__ xgb,
                                                 unsigned short* __restrict__ xub) {
  int e = blockIdx.x >> 1, half = blockIdx.x & 1;
  int g = e >> 5;
  __shared__ float cg[4096], cu[4096];
  __shared__ float rg[4][64], ru[4][64];
  int tid = threadIdx.x;
  for (int i = tid; i < 1024; i += 256) {
    *(float4*)&cg[i * 4] = *(const float4*)&core_g[(size_t)e * 4096 + (size_t)i * 4];
    *(float4*)&cu[i * 4] = *(const float4*)&core_u[(size_t)e * 4096 + (size_t)i * 4];
  }
  int p0 = off[e], n = off[e + 1] - p0;
  int hn = (n + 1) >> 1;
  int i0 = half * hn;
  int i1 = i0 + hn; if (i1 > n) i1 = n;
  int pl = tid >> 6, o = tid & 63;
  __syncthreads();
  for (int ib = i0; ib < i1; ib += 4) {
    int i = ib + pl;
    bool valid = i < i1;
    int p = p0 + i;
    float sg = 0.f, su = 0.f;
    if (valid) {
      int t = bucket[e * 1024 + i] >> 3;
#pragma unroll
      for (int kz = 0; kz < PKZ_; ++kz) {
        sg += Pgp[((size_t)(kz * G_ + g) * T_ + t) * R_ + o];
        su += Pup[((size_t)(kz * G_ + g) * T_ + t) * R_ + o];
      }
    }
    __syncthreads();
    rg[pl][o] = sg;
    ru[pl][o] = su;
    __syncthreads();
    if (valid) {
      float ag = 0.f, au = 0.f;
#pragma unroll 8
      for (int r = 0; r < R_; ++r) {
        ag = fmaf(rg[pl][r], cg[r * R_ + o], ag);
        au = fmaf(ru[pl][r], cu[r * R_ + o], au);
      }
      xgb[(size_t)p * R_ + o] = f2bf(ag);
      xub[(size_t)p * R_ + o] = f2bf(au);
    }
  }
}

// ---------------------------------------------------------------- D4: fused act+down (MFMA)
__global__ __launch_bounds__(256) void k_fused_ad(const unsigned short* __restrict__ xgb,
                                                  const unsigned short* __restrict__ xub,
                                                  const unsigned short* __restrict__ uoutT_g,
                                                  const unsigned short* __restrict__ uoutT_u,
                                                  const unsigned short* __restrict__ uinT_d,
                                                  const int* __restrict__ off,
                                                  float* __restrict__ xdp) {
  int g = blockIdx.y;
  int kz = blockIdx.z;
  int p0 = off[g * E_];
  int pend = off[g * E_ + E_];
  int ntiles = (pend - p0 + 63) >> 6;
  __shared__ short Ag[64 * LP_], Au[64 * LP_];
  __shared__ short Bg[64 * LP_], Bu[64 * LP_], Bd[64 * LP_];
  __shared__ short Pt[64 * LP_];
  int tid = threadIdx.x, lane = tid & 63, ms = (tid >> 6) * 16;
  int lm = lane & 15, lq = (lane >> 4) * 4;
  for (int tile = blockIdx.x; tile < ntiles; tile += gridDim.x) {
    int pbase = p0 + tile * 64;
    int rv = pend - pbase; if (rv > 64) rv = 64;
    stage_tile_guard(Ag, xgb + (size_t)pbase * R_, R_, rv, tid);
    stage_tile_guard(Au, xub + (size_t)pbase * R_, R_, rv, tid);
    f32x4 accd[4] = {};
#pragma unroll
    for (int c4 = 0; c4 < 4; ++c4) {
      int cc = kz * (DFF_ / DKZ_) + c4 * 64;
      stage_tile(Bg, uoutT_g + ((size_t)g * DFF_ + cc) * R_, R_, tid);
      stage_tile(Bu, uoutT_u + ((size_t)g * DFF_ + cc) * R_, R_, tid);
      stage_tile(Bd, uinT_d + (size_t)g * 64 * 1024 + cc, 1024, tid);
      __syncthreads();
      f32x4 accg[4] = {}, accu[4] = {};
      mma_strip(Ag, Bg, ms, lane, accg);
      mma_strip(Au, Bu, ms, lane, accu);
#pragma unroll
      for (int nt = 0; nt < 4; ++nt)
#pragma unroll
        for (int r = 0; r < 4; ++r) {
          float gv = accg[nt][r];
          float av = gv / (1.f + expf(-gv)) * accu[nt][r];
          Pt[(ms + lq + r) * LP_ + nt * 16 + lm] = (short)f2bf(av);
        }
      mma_strip(Pt, Bd, ms, lane, accd);  // reads only own-wave rows of Pt
      __syncthreads();
    }
#pragma unroll
    for (int nt = 0; nt < 4; ++nt)
#pragma unroll
      for (int r = 0; r < 4; ++r) {
        int p = pbase + ms + lq + r;
        if (p < pend) xdp[((size_t)kz * F_ + p) * R_ + nt * 16 + lm] = accd[nt][r];
      }
    __syncthreads();
  }
}

// ---------------------------------------------------------------- D5: per-expert fold xdp + down core + wsm -> atomic Y
__global__ __launch_bounds__(256) void k_down_core(const float* __restrict__ xdp,
                                                   const float* __restrict__ core_d,
                                                   const int* __restrict__ bucket,
                                                   const float* __restrict__ wsm,
                                                   const int* __restrict__ off,
                                                   float* __restrict__ Yf) {
  int e = blockIdx.x >> 1, half = blockIdx.x & 1;
  int g = e >> 5;
  __shared__ float cd[4096];
  __shared__ float xs[4][64];
  int tid = threadIdx.x;
  for (int i = tid; i < 1024; i += 256)
    *(float4*)&cd[i * 4] = *(const float4*)&core_d[(size_t)e * 4096 + (size_t)i * 4];
  int p0 = off[e], n = off[e + 1] - p0;
  int hn = (n + 1) >> 1;
  int i0 = half * hn;
  int i1 = i0 + hn; if (i1 > n) i1 = n;
  int pl = tid >> 6, o = tid & 63;
  __syncthreads();
  for (int ib = i0; ib < i1; ib += 4) {
    int i = ib + pl;
    bool valid = i < i1;
    int p = p0 + i;
    int f = valid ? bucket[e * 1024 + i] : 0;
    float s = 0.f;
    if (valid) {
#pragma unroll
      for (int kz = 0; kz < DKZ_; ++kz) s += xdp[((size_t)kz * F_ + p) * R_ + o];
    }
    __syncthreads();
    xs[pl][o] = s;
    __syncthreads();
    if (valid) {
      float a = 0.f;
#pragma unroll 8
      for (int r = 0; r < R_; ++r) a = fmaf(xs[pl][r], cd[r * R_ + o], a);
      atomicAdd(&Yf[(size_t)(f >> 3) * 512 + g * 64 + o], wsm[f] * a);
    }
  }
}

// ---------------------------------------------------------------- D6: out = Y[1024,512] @ Uod2[512,1024], dense MFMA
__global__ __launch_bounds__(256) void k_fin(const float* __restrict__ Yf,
                                             const unsigned short* __restrict__ Uod2T,
                                             float* __restrict__ out) {
  int t0 = blockIdx.x * 64;
  int d0 = blockIdx.y * 64;
  __shared__ short As[64 * LP_], Bs[64 * LP_];
  __shared__ float Os[64 * 68];
  int tid = threadIdx.x, lane = tid & 63, ms = (tid >> 6) * 16;
  int lm = lane & 15, lq = (lane >> 4) * 4;
  f32x4 acc[4] = {};
  for (int kc = 0; kc < 512; kc += 64) {
    stage_tile_f32(As, Yf + (size_t)t0 * 512 + kc, 512, tid);
    stage_tile(Bs, Uod2T + (size_t)d0 * 512 + kc, 512, tid);
    __syncthreads();
    mma_strip(As, Bs, ms, lane, acc);
    __syncthreads();
  }
#pragma unroll
  for (int nt = 0; nt < 4; ++nt)
#pragma unroll
    for (int r = 0; r < 4; ++r)
      Os[(ms + lq + r) * 68 + nt * 16 + lm] = acc[nt][r];
  __syncthreads();
  for (int idx = tid; idx < 1024; idx += 256) {
    int r = idx >> 4, c4 = (idx & 15) << 2;
    *(float4*)&out[(size_t)(t0 + r) * D_ + d0 + c4] = *(const float4*)&Os[r * 68 + c4];
  }
}

// ================================================================ launch
extern "C" void kernel_launch(void* const* d_in, const int* in_sizes, int n_in,
                              void* d_out, int out_size, void* d_ws, size_t ws_size,
                              hipStream_t stream) {
  const float* x = (const float*)d_in[0];
  const float* Wg = (const float*)d_in[1];
  const float* uin_gate = (const float*)d_in[2];
  const float* core_gate = (const float*)d_in[3];
  const float* uout_gate = (const float*)d_in[4];
  const float* uin_up = (const float*)d_in[5];
  const float* core_up = (const float*)d_in[6];
  const float* uout_up = (const float*)d_in[7];
  const float* uin_down = (const float*)d_in[8];
  const float* core_down = (const float*)d_in[9];
  const float* uout_down = (const float*)d_in[10];
  float* out = (float*)d_out;

  char* ws = (char*)d_ws;
  size_t o = 0;
  auto alloc = [&](size_t bytes) { size_t r = o; o = (o + bytes + 255) & ~(size_t)255; return r; };
  size_t o_wsm = alloc(F_ * 4);
  size_t o_bucket = alloc((size_t)NEXP_ * 1024 * 4);            // 1 MB
  size_t o_cnt = alloc(NEXP_ * 4);
  size_t o_tickets = alloc(256);
  size_t o_off = alloc((NEXP_ + 1) * 4);
  size_t o_xb = alloc((size_t)T_ * D_ * 2);                     // 2 MB
  size_t o_uinT_g = alloc((size_t)G_ * 64 * 1024 * 2);          // 1 MB each
  size_t o_uinT_u = alloc((size_t)G_ * 64 * 1024 * 2);
  size_t o_uinT_d = alloc((size_t)G_ * 64 * 1024 * 2);
  size_t o_uoutT_g = alloc((size_t)G_ * 1024 * 64 * 2);
  size_t o_uoutT_u = alloc((size_t)G_ * 1024 * 64 * 2);
  size_t o_Uod2T = alloc((size_t)D_ * 512 * 2);                 // 1 MB
  size_t o_xgb = alloc((size_t)F_ * R_ * 2);                    // 1 MB
  size_t o_xub = alloc((size_t)F_ * R_ * 2);
  size_t o_Y = alloc((size_t)T_ * 512 * 4);                     // 2 MB fp32
  size_t o_pgp = alloc((size_t)PKZ_ * G_ * T_ * R_ * 4);        // 4 MB
  size_t o_pup = alloc((size_t)PKZ_ * G_ * T_ * R_ * 4);        // 4 MB
  size_t o_xdp = alloc((size_t)DKZ_ * F_ * R_ * 4);             // 8 MB
  (void)ws_size;

  float* wsm = (float*)(ws + o_wsm);
  int* bucket = (int*)(ws + o_bucket);
  int* cnt = (int*)(ws + o_cnt);
  int* tickets = (int*)(ws + o_tickets);
  int* off = (int*)(ws + o_off);
  unsigned short* xb = (unsigned short*)(ws + o_xb);
  unsigned short* uinT_g = (unsigned short*)(ws + o_uinT_g);
  unsigned short* uinT_u = (unsigned short*)(ws + o_uinT_u);
  unsigned short* uinT_d = (unsigned short*)(ws + o_uinT_d);
  unsigned short* uoutT_g = (unsigned short*)(ws + o_uoutT_g);
  unsigned short* uoutT_u = (unsigned short*)(ws + o_uoutT_u);
  unsigned short* Uod2T = (unsigned short*)(ws + o_Uod2T);
  unsigned short* xgb = (unsigned short*)(ws + o_xgb);
  unsigned short* xub = (unsigned short*)(ws + o_xub);
  float* Yf = (float*)(ws + o_Y);
  float* pgp = (float*)(ws + o_pgp);
  float* pup = (float*)(ws + o_pup);
  float* xdp = (float*)(ws + o_xdp);

  k_prep<<<896, 256, 0, stream>>>(x, uin_gate, uin_up, uin_down,
                                  uout_gate, uout_up, uout_down, xb,
                                  uinT_g, uinT_u, uinT_d,
                                  uoutT_g, uoutT_u, Uod2T, cnt, tickets, Yf);
  k_pre_router<<<640, 256, 0, stream>>>(x, Wg, xb, uinT_g, uinT_u,
                                        pgp, pup, wsm, bucket, cnt, tickets, off);
  k_core_gu<<<NEXP_ * 2, 256, 0, stream>>>(pgp, pup, core_gate, core_up, bucket, off, xgb, xub);
  k_fused_ad<<<dim3(16, G_, DKZ_), 256, 0, stream>>>(xgb, xub, uoutT_g, uoutT_u, uinT_d, off, xdp);
  k_down_core<<<NEXP_ * 2, 256, 0, stream>>>(xdp, core_down, bucket, wsm, off, Yf);
  k_fin<<<dim3(16, 16), 256, 0, stream>>>(Yf, Uod2T, out);
}

// Round 4
// 218.807 us; speedup vs baseline: 1.0950x; 1.0950x over previous
//
#include <hip/hip_runtime.h>
#include <hip/hip_bf16.h>
#include <math.h>

// Tucker MoE: T=1024, D=1024, DFF=1024, R=64, G=8, E=32, NEXP=256, K=8, F=8192
// Round 13: fix r12's router serialization (k_pre_router was 100us, VALUBusy
// 10%, Occ 9% -- latency-bound, 128 blocks with 256-iter serial chains).
//  - router now 256 blocks x 4 tokens, split-K across the 4 WAVES
//    (wave w owns d in [256w,256w+256), 64-iter chain, 16 accumulators).
//    Partials folded via LDS part[w][t][e] (conflict-free), fold order
//    w-ascending == r11's split-K fold (bit-identical logits).
//  - topk + bucket + ticket + scan tail unchanged (in-dispatch).
//  - everything else unchanged from r12.
// 6 dispatches:
//  D1 k_prep       : casts/transposes + cnt/tickets/Y zero
//  D2 k_pre_router : router+topk+scan (256 blk) || pre MFMA (512 blk)
//  D3 k_core_gu    : per-expert gate/up core (LDS, fp32) -> xgb/xub[p]
//  D4 k_fused_ad   : act(gate/up MFMA + silu*mul in LDS) fused w/ down MFMA
//  D5 k_down_core  : per-expert fold xdp + down core + wsm -> atomic Y fp32
//  D6 k_fin        : dense out = Y[1024,512] @ Uod2[512,1024] (bf16 MFMA)

#define T_ 1024
#define D_ 1024
#define DFF_ 1024
#define R_ 64
#define G_ 8
#define E_ 32
#define NEXP_ 256
#define K_ 8
#define F_ 8192
#define PKZ_ 2   // k_pre split-K
#define DKZ_ 4   // down split-K (chunks of 256 over DFF)
#define LP_ 72   // LDS tile pitch in bf16 elems (16B rows, 2-way bank alias = free)

typedef short bf16x8 __attribute__((ext_vector_type(8)));
typedef float f32x4 __attribute__((ext_vector_type(4)));

__device__ __forceinline__ unsigned short f2bf(float f) {
  unsigned int u = __float_as_uint(f);
  u += 0x7fffu + ((u >> 16) & 1u);  // RNE (finite inputs)
  return (unsigned short)(u >> 16);
}

__device__ __forceinline__ void stage_tile(short* dst, const unsigned short* src,
                                           int gp, int tid) {
  for (int idx = tid; idx < 512; idx += 256) {
    int r = idx >> 3, c8 = (idx & 7) << 3;
    *(uint4*)&dst[r * LP_ + c8] = *(const uint4*)&src[(size_t)r * gp + c8];
  }
}

__device__ __forceinline__ void stage_tile_guard(short* dst, const unsigned short* src,
                                                 int gp, int rows_valid, int tid) {
  for (int idx = tid; idx < 512; idx += 256) {
    int r = idx >> 3, c8 = (idx & 7) << 3;
    uint4 v = make_uint4(0u, 0u, 0u, 0u);
    if (r < rows_valid) v = *(const uint4*)&src[(size_t)r * gp + c8];
    *(uint4*)&dst[r * LP_ + c8] = v;
  }
}

// Stage a 64x64 bf16 tile from an fp32 source (convert on the fly).
__device__ __forceinline__ void stage_tile_f32(short* dst, const float* src,
                                               int gp, int tid) {
  for (int idx = tid; idx < 512; idx += 256) {
    int r = idx >> 3, c8 = (idx & 7) << 3;
    const float* s = &src[(size_t)r * gp + c8];
    float4 v0 = *(const float4*)s;
    float4 v1 = *(const float4*)(s + 4);
    uint4 u;
    u.x = ((unsigned)f2bf(v0.y) << 16) | f2bf(v0.x);
    u.y = ((unsigned)f2bf(v0.w) << 16) | f2bf(v0.z);
    u.z = ((unsigned)f2bf(v1.y) << 16) | f2bf(v1.x);
    u.w = ((unsigned)f2bf(v1.w) << 16) | f2bf(v1.z);
    *(uint4*)&dst[r * LP_ + c8] = u;
  }
}

// Wave computes a 16x64 strip (rows [ms,ms+16)) over K=64 from LDS tiles
// As (rows=m, k-contig) and Bs (rows=n, k-contig; i.e. B^T).
__device__ __forceinline__ void mma_strip(const short* As, const short* Bs,
                                          int ms, int lane, f32x4* acc) {
  int lm = lane & 15;
  int lk = (lane >> 4) << 3;
#pragma unroll
  for (int kc = 0; kc < 64; kc += 32) {
    bf16x8 a = *(const bf16x8*)&As[(ms + lm) * LP_ + kc + lk];
#pragma unroll
    for (int nt = 0; nt < 4; ++nt) {
      bf16x8 b = *(const bf16x8*)&Bs[(nt * 16 + lm) * LP_ + kc + lk];
      acc[nt] = __builtin_amdgcn_mfma_f32_16x16x32_bf16(a, b, acc[nt], 0, 0, 0);
    }
  }
}

// ---------------------------------------------------------------- D1: prep
// 896 blocks: id=b>>7: 0..4 cast+T, id 5 = uout_down -> Uod2T[d][g*64+r],
// id 6 = x cast + cnt/tickets zero + Y zero.
__global__ __launch_bounds__(256) void k_prep(
    const float* __restrict__ x,
    const float* __restrict__ s0, const float* __restrict__ s1,
    const float* __restrict__ s2, const float* __restrict__ s3,
    const float* __restrict__ s4, const float* __restrict__ s5,
    unsigned short* __restrict__ xb,
    unsigned short* __restrict__ d0, unsigned short* __restrict__ d1,
    unsigned short* __restrict__ d2, unsigned short* __restrict__ d3,
    unsigned short* __restrict__ d4, unsigned short* __restrict__ d5,
    int* __restrict__ cnt, int* __restrict__ tickets, float* __restrict__ Yf) {
  __shared__ float shbuf[64 * 65];
  int b = blockIdx.x;
  int id = b >> 7, rem = b & 127, g = rem >> 4, tile = rem & 15;
  if (id == 6) {
    size_t base = ((size_t)g * 16 + tile) * 8192;
    for (int i = threadIdx.x; i < 2048; i += 256) {
      size_t idx = base + (size_t)i * 4;
      float4 v = *(const float4*)&x[idx];
      xb[idx + 0] = f2bf(v.x);
      xb[idx + 1] = f2bf(v.y);
      xb[idx + 2] = f2bf(v.z);
      xb[idx + 3] = f2bf(v.w);
    }
    // zero Y: 128 blocks x 4096 floats = 1024x512
    size_t ybase = ((size_t)g * 16 + tile) * 4096;
    float4 z4 = make_float4(0.f, 0.f, 0.f, 0.f);
    for (int i = threadIdx.x; i < 1024; i += 256)
      *(float4*)&Yf[ybase + (size_t)i * 4] = z4;
    if (g == 0 && tile == 0) {
      cnt[threadIdx.x] = 0;
      if (threadIdx.x == 0) tickets[0] = 0;
    }
    return;
  }
  const float* src = id == 0 ? s0 : id == 1 ? s1 : id == 2 ? s2 : id == 3 ? s3 : id == 4 ? s4 : s5;
  unsigned short* dst = id == 0 ? d0 : id == 1 ? d1 : id == 2 ? d2 : id == 3 ? d3 : id == 4 ? d4 : d5;
  if (id < 3) {
    // uin*: src [g][1024][64] -> dst [g][64][1024]
    int r0 = tile * 64;
    for (int idx = threadIdx.x; idx < 4096; idx += 256) {
      int r = idx >> 6, c = idx & 63;
      shbuf[r * 65 + c] = src[((size_t)g * 1024 + r0 + r) * 64 + c];
    }
    __syncthreads();
    for (int idx = threadIdx.x; idx < 4096; idx += 256) {
      int c = idx >> 6, r = idx & 63;
      dst[((size_t)g * 64 + c) * 1024 + r0 + r] = f2bf(shbuf[r * 65 + c]);
    }
  } else {
    // uout*: src [g][64][1024]; id 3/4 -> [g][1024][64]; id 5 -> [d][g*64+r]
    int c0 = tile * 64;
    for (int idx = threadIdx.x; idx < 4096; idx += 256) {
      int r = idx >> 6, c = idx & 63;
      shbuf[r * 65 + c] = src[((size_t)g * 64 + r) * 1024 + c0 + c];
    }
    __syncthreads();
    if (id == 5) {
      for (int idx = threadIdx.x; idx < 4096; idx += 256) {
        int c = idx >> 6, r = idx & 63;
        dst[(size_t)(c0 + c) * 512 + g * 64 + r] = f2bf(shbuf[r * 65 + c]);
      }
    } else {
      for (int idx = threadIdx.x; idx < 4096; idx += 256) {
        int c = idx >> 6, r = idx & 63;
        dst[((size_t)g * 1024 + c0 + c) * 64 + r] = f2bf(shbuf[r * 65 + c]);
      }
    }
  }
}

// ---------------------------------------------------------------- D2: router+topk+scan || pre MFMA
// Grid 768: b<256 = router blocks (4 tokens each, split-K across the 4 waves;
// topk per wave; LAST router block scans cnt->off). b>=256 = 512 pre-MFMA blocks.
__global__ __launch_bounds__(256) void k_pre_router(
    const float* __restrict__ x, const float* __restrict__ Wg,
    const unsigned short* __restrict__ xb,
    const unsigned short* __restrict__ uinT_g, const unsigned short* __restrict__ uinT_u,
    float* __restrict__ Pgp, float* __restrict__ Pup,
    float* __restrict__ wsm, int* __restrict__ bucket, int* __restrict__ cnt,
    int* __restrict__ tickets, int* __restrict__ off) {
  __shared__ float smf[8192];  // 32 KB union: {xs[4][1024], part[4][4][256]} / MFMA tiles / scan
  __shared__ int lastfl;
  int b = blockIdx.x;
  int tid = threadIdx.x;
  if (b >= 256) {
    int b2 = b - 256;
    int tile = b2 & 15, g = (b2 >> 4) & 7, zz = b2 >> 7;
    int gu = zz >> 1, kz = zz & 1;
    const unsigned short* U = gu ? uinT_u : uinT_g;  // [G][64(r)][1024(d)]
    float* P = gu ? Pup : Pgp;
    int t0 = tile * 64;
    short* As = (short*)smf;
    short* Bs = (short*)smf + 64 * LP_;
    int lane = tid & 63, ms = (tid >> 6) * 16;
    f32x4 acc[4] = {};
    int dlo = kz * (D_ / PKZ_);
    for (int dc = dlo; dc < dlo + D_ / PKZ_; dc += 64) {
      stage_tile(As, xb + (size_t)t0 * D_ + dc, D_, tid);
      stage_tile(Bs, U + (size_t)g * 64 * 1024 + dc, 1024, tid);
      __syncthreads();
      mma_strip(As, Bs, ms, lane, acc);
      __syncthreads();
    }
    int lm = lane & 15, lq = (lane >> 4) * 4;
#pragma unroll
    for (int nt = 0; nt < 4; ++nt)
#pragma unroll
      for (int r = 0; r < 4; ++r)
        P[((size_t)(kz * G_ + g) * T_ + t0 + ms + lq + r) * R_ + nt * 16 + lm] = acc[nt][r];
    return;
  }
  // ---- router: 4 tokens/block; wave w owns d-chunk [256w, 256w+256)
  int t0 = b * 4;
  float* xs = smf;           // [4][1024]
  float* part = smf + 4096;  // [w][t][e] = [4][4][256]
  for (int i = tid; i < 1024; i += 256) {
    int j = i >> 8, d4 = (i & 255) << 2;
    *(float4*)&xs[j * 1024 + d4] = *(const float4*)&x[(size_t)(t0 + j) * D_ + d4];
  }
  __syncthreads();
  int wv = tid >> 6, lane = tid & 63;
  int dbase = wv * 256;
  float a00 = 0.f, a01 = 0.f, a02 = 0.f, a03 = 0.f;
  float a10 = 0.f, a11 = 0.f, a12 = 0.f, a13 = 0.f;
  float a20 = 0.f, a21 = 0.f, a22 = 0.f, a23 = 0.f;
  float a30 = 0.f, a31 = 0.f, a32 = 0.f, a33 = 0.f;
#pragma unroll 2
  for (int d2 = 0; d2 < 256; d2 += 4) {
    int d = dbase + d2;
    float4 xv0 = *(const float4*)&xs[0 * 1024 + d];
    float4 xv1 = *(const float4*)&xs[1 * 1024 + d];
    float4 xv2 = *(const float4*)&xs[2 * 1024 + d];
    float4 xv3 = *(const float4*)&xs[3 * 1024 + d];
#pragma unroll
    for (int j = 0; j < 4; ++j) {
      int e = lane + 64 * j;
      float w0 = Wg[(size_t)(d + 0) * NEXP_ + e];
      float w1 = Wg[(size_t)(d + 1) * NEXP_ + e];
      float w2 = Wg[(size_t)(d + 2) * NEXP_ + e];
      float w3 = Wg[(size_t)(d + 3) * NEXP_ + e];
      float t00 = j == 0 ? a00 : j == 1 ? a10 : j == 2 ? a20 : a30;
      float t01 = j == 0 ? a01 : j == 1 ? a11 : j == 2 ? a21 : a31;
      float t02 = j == 0 ? a02 : j == 1 ? a12 : j == 2 ? a22 : a32;
      float t03 = j == 0 ? a03 : j == 1 ? a13 : j == 2 ? a23 : a33;
      t00 = fmaf(xv0.x, w0, t00); t00 = fmaf(xv0.y, w1, t00);
      t00 = fmaf(xv0.z, w2, t00); t00 = fmaf(xv0.w, w3, t00);
      t01 = fmaf(xv1.x, w0, t01); t01 = fmaf(xv1.y, w1, t01);
      t01 = fmaf(xv1.z, w2, t01); t01 = fmaf(xv1.w, w3, t01);
      t02 = fmaf(xv2.x, w0, t02); t02 = fmaf(xv2.y, w1, t02);
      t02 = fmaf(xv2.z, w2, t02); t02 = fmaf(xv2.w, w3, t02);
      t03 = fmaf(xv3.x, w0, t03); t03 = fmaf(xv3.y, w1, t03);
      t03 = fmaf(xv3.z, w2, t03); t03 = fmaf(xv3.w, w3, t03);
      if (j == 0) { a00 = t00; a01 = t01; a02 = t02; a03 = t03; }
      else if (j == 1) { a10 = t00; a11 = t01; a12 = t02; a13 = t03; }
      else if (j == 2) { a20 = t00; a21 = t01; a22 = t02; a23 = t03; }
      else { a30 = t00; a31 = t01; a32 = t02; a33 = t03; }
    }
  }
  // write partials: part[wv][t][e], lane-stride 4B (conflict-free)
  part[(wv * 4 + 0) * 256 + lane + 0]   = a00;
  part[(wv * 4 + 1) * 256 + lane + 0]   = a01;
  part[(wv * 4 + 2) * 256 + lane + 0]   = a02;
  part[(wv * 4 + 3) * 256 + lane + 0]   = a03;
  part[(wv * 4 + 0) * 256 + lane + 64]  = a10;
  part[(wv * 4 + 1) * 256 + lane + 64]  = a11;
  part[(wv * 4 + 2) * 256 + lane + 64]  = a12;
  part[(wv * 4 + 3) * 256 + lane + 64]  = a13;
  part[(wv * 4 + 0) * 256 + lane + 128] = a20;
  part[(wv * 4 + 1) * 256 + lane + 128] = a21;
  part[(wv * 4 + 2) * 256 + lane + 128] = a22;
  part[(wv * 4 + 3) * 256 + lane + 128] = a23;
  part[(wv * 4 + 0) * 256 + lane + 192] = a30;
  part[(wv * 4 + 1) * 256 + lane + 192] = a31;
  part[(wv * 4 + 2) * 256 + lane + 192] = a32;
  part[(wv * 4 + 3) * 256 + lane + 192] = a33;
  __syncthreads();
  // ---- wave wv folds + topk for token t0+wv (fold order w-ascending == r11)
  {
    int tt = wv;
    int t = t0 + tt;
    float v[4];
    int idx[4];
#pragma unroll
    for (int j2 = 0; j2 < 4; ++j2) {
      int e = lane + 64 * j2;
      idx[j2] = e;
      v[j2] = part[(0 * 4 + tt) * 256 + e] + part[(1 * 4 + tt) * 256 + e]
            + part[(2 * 4 + tt) * 256 + e] + part[(3 * 4 + tt) * 256 + e];
    }
    float topv[K_];
    int topi[K_];
#pragma unroll
    for (int k = 0; k < K_; ++k) {
      float bv = v[0];
      int bi = idx[0];
#pragma unroll
      for (int j2 = 1; j2 < 4; ++j2)
        if (v[j2] > bv || (v[j2] == bv && idx[j2] < bi)) { bv = v[j2]; bi = idx[j2]; }
#pragma unroll
      for (int o2 = 32; o2 > 0; o2 >>= 1) {
        float ov = __shfl_xor(bv, o2);
        int oi = __shfl_xor(bi, o2);
        if (ov > bv || (ov == bv && oi < bi)) { bv = ov; bi = oi; }
      }
      topv[k] = bv;
      topi[k] = bi;
#pragma unroll
      for (int j2 = 0; j2 < 4; ++j2)
        if (idx[j2] == bi) v[j2] = -INFINITY;
    }
    float m = topv[0];
    float ev[K_];
    float s = 0.f;
#pragma unroll
    for (int k = 0; k < K_; ++k) { ev[k] = expf(topv[k] - m); s += ev[k]; }
    float inv = 1.f / s;
    if (lane < K_) {
      wsm[t * K_ + lane] = ev[lane] * inv;
      int r1 = atomicAdd(&cnt[topi[lane]], 1);
      bucket[topi[lane] * 1024 + r1] = t * K_ + lane;
    }
  }
  // ---- last router block scans cnt -> off
  __threadfence();
  __syncthreads();
  if (tid == 0) lastfl = (atomicAdd(&tickets[0], 1) == 255) ? 1 : 0;
  __syncthreads();
  if (lastfl) {
    int* s = (int*)smf;
    int i = tid;
    int c0 = atomicAdd(&cnt[i], 0);  // coherent read of final counts
    s[i] = c0;
    __syncthreads();
    for (int d = 1; d < NEXP_; d <<= 1) {
      int vv = (i >= d) ? s[i - d] : 0;
      __syncthreads();
      s[i] += vv;
      __syncthreads();
    }
    off[i + 1] = s[i];
    if (i == 0) off[0] = 0;
  }
}

// ---------------------------------------------------------------- D3: per-expert gate/up core -> xgb/xub[p]
__global__ __launch_bounds__(256) void k_core_gu(const float* __restrict__ Pgp,
                                                 const float* __restrict__ Pup,
                                                 const float* __restrict__ core_g,
                                                 const float* __restrict__ core_u,
                                                 const int* __restrict__ bucket,
                                                 const int* __restrict__ off,
                                                 unsigned short* __restrict__ xgb,
                                                 unsigned short* __restrict__ xub) {
  int e = blockIdx.x >> 1, half = blockIdx.x & 1;
  int g = e >> 5;
  __shared__ float cg[4096], cu[4096];
  __shared__ float rg[4][64], ru[4][64];
  int tid = threadIdx.x;
  for (int i = tid; i < 1024; i += 256) {
    *(float4*)&cg[i * 4] = *(const float4*)&core_g[(size_t)e * 4096 + (size_t)i * 4];
    *(float4*)&cu[i * 4] = *(const float4*)&core_u[(size_t)e * 4096 + (size_t)i * 4];
  }
  int p0 = off[e], n = off[e + 1] - p0;
  int hn = (n + 1) >> 1;
  int i0 = half * hn;
  int i1 = i0 + hn; if (i1 > n) i1 = n;
  int pl = tid >> 6, o = tid & 63;
  __syncthreads();
  for (int ib = i0; ib < i1; ib += 4) {
    int i = ib + pl;
    bool valid = i < i1;
    int p = p0 + i;
    float sg = 0.f, su = 0.f;
    if (valid) {
      int t = bucket[e * 1024 + i] >> 3;
#pragma unroll
      for (int kz = 0; kz < PKZ_; ++kz) {
        sg += Pgp[((size_t)(kz * G_ + g) * T_ + t) * R_ + o];
        su += Pup[((size_t)(kz * G_ + g) * T_ + t) * R_ + o];
      }
    }
    __syncthreads();
    rg[pl][o] = sg;
    ru[pl][o] = su;
    __syncthreads();
    if (valid) {
      float ag = 0.f, au = 0.f;
#pragma unroll 8
      for (int r = 0; r < R_; ++r) {
        ag = fmaf(rg[pl][r], cg[r * R_ + o], ag);
        au = fmaf(ru[pl][r], cu[r * R_ + o], au);
      }
      xgb[(size_t)p * R_ + o] = f2bf(ag);
      xub[(size_t)p * R_ + o] = f2bf(au);
    }
  }
}

// ---------------------------------------------------------------- D4: fused act+down (MFMA)
__global__ __launch_bounds__(256) void k_fused_ad(const unsigned short* __restrict__ xgb,
                                                  const unsigned short* __restrict__ xub,
                                                  const unsigned short* __restrict__ uoutT_g,
                                                  const unsigned short* __restrict__ uoutT_u,
                                                  const unsigned short* __restrict__ uinT_d,
                                                  const int* __restrict__ off,
                                                  float* __restrict__ xdp) {
  int g = blockIdx.y;
  int kz = blockIdx.z;
  int p0 = off[g * E_];
  int pend = off[g * E_ + E_];
  int ntiles = (pend - p0 + 63) >> 6;
  __shared__ short Ag[64 * LP_], Au[64 * LP_];
  __shared__ short Bg[64 * LP_], Bu[64 * LP_], Bd[64 * LP_];
  __shared__ short Pt[64 * LP_];
  int tid = threadIdx.x, lane = tid & 63, ms = (tid >> 6) * 16;
  int lm = lane & 15, lq = (lane >> 4) * 4;
  for (int tile = blockIdx.x; tile < ntiles; tile += gridDim.x) {
    int pbase = p0 + tile * 64;
    int rv = pend - pbase; if (rv > 64) rv = 64;
    stage_tile_guard(Ag, xgb + (size_t)pbase * R_, R_, rv, tid);
    stage_tile_guard(Au, xub + (size_t)pbase * R_, R_, rv, tid);
    f32x4 accd[4] = {};
#pragma unroll
    for (int c4 = 0; c4 < 4; ++c4) {
      int cc = kz * (DFF_ / DKZ_) + c4 * 64;
      stage_tile(Bg, uoutT_g + ((size_t)g * DFF_ + cc) * R_, R_, tid);
      stage_tile(Bu, uoutT_u + ((size_t)g * DFF_ + cc) * R_, R_, tid);
      stage_tile(Bd, uinT_d + (size_t)g * 64 * 1024 + cc, 1024, tid);
      __syncthreads();
      f32x4 accg[4] = {}, accu[4] = {};
      mma_strip(Ag, Bg, ms, lane, accg);
      mma_strip(Au, Bu, ms, lane, accu);
#pragma unroll
      for (int nt = 0; nt < 4; ++nt)
#pragma unroll
        for (int r = 0; r < 4; ++r) {
          float gv = accg[nt][r];
          float av = gv / (1.f + expf(-gv)) * accu[nt][r];
          Pt[(ms + lq + r) * LP_ + nt * 16 + lm] = (short)f2bf(av);
        }
      mma_strip(Pt, Bd, ms, lane, accd);  // reads only own-wave rows of Pt
      __syncthreads();
    }
#pragma unroll
    for (int nt = 0; nt < 4; ++nt)
#pragma unroll
      for (int r = 0; r < 4; ++r) {
        int p = pbase + ms + lq + r;
        if (p < pend) xdp[((size_t)kz * F_ + p) * R_ + nt * 16 + lm] = accd[nt][r];
      }
    __syncthreads();
  }
}

// ---------------------------------------------------------------- D5: per-expert fold xdp + down core + wsm -> atomic Y
__global__ __launch_bounds__(256) void k_down_core(const float* __restrict__ xdp,
                                                   const float* __restrict__ core_d,
                                                   const int* __restrict__ bucket,
                                                   const float* __restrict__ wsm,
                                                   const int* __restrict__ off,
                                                   float* __restrict__ Yf) {
  int e = blockIdx.x >> 1, half = blockIdx.x & 1;
  int g = e >> 5;
  __shared__ float cd[4096];
  __shared__ float xs[4][64];
  int tid = threadIdx.x;
  for (int i = tid; i < 1024; i += 256)
    *(float4*)&cd[i * 4] = *(const float4*)&core_d[(size_t)e * 4096 + (size_t)i * 4];
  int p0 = off[e], n = off[e + 1] - p0;
  int hn = (n + 1) >> 1;
  int i0 = half * hn;
  int i1 = i0 + hn; if (i1 > n) i1 = n;
  int pl = tid >> 6, o = tid & 63;
  __syncthreads();
  for (int ib = i0; ib < i1; ib += 4) {
    int i = ib + pl;
    bool valid = i < i1;
    int p = p0 + i;
    int f = valid ? bucket[e * 1024 + i] : 0;
    float s = 0.f;
    if (valid) {
#pragma unroll
      for (int kz = 0; kz < DKZ_; ++kz) s += xdp[((size_t)kz * F_ + p) * R_ + o];
    }
    __syncthreads();
    xs[pl][o] = s;
    __syncthreads();
    if (valid) {
      float a = 0.f;
#pragma unroll 8
      for (int r = 0; r < R_; ++r) a = fmaf(xs[pl][r], cd[r * R_ + o], a);
      atomicAdd(&Yf[(size_t)(f >> 3) * 512 + g * 64 + o], wsm[f] * a);
    }
  }
}

// ---------------------------------------------------------------- D6: out = Y[1024,512] @ Uod2[512,1024], dense MFMA
__global__ __launch_bounds__(256) void k_fin(const float* __restrict__ Yf,
                                             const unsigned short* __restrict__ Uod2T,
                                             float* __restrict__ out) {
  int t0 = blockIdx.x * 64;
  int d0 = blockIdx.y * 64;
  __shared__ short As[64 * LP_], Bs[64 * LP_];
  __shared__ float Os[64 * 68];
  int tid = threadIdx.x, lane = tid & 63, ms = (tid >> 6) * 16;
  int lm = lane & 15, lq = (lane >> 4) * 4;
  f32x4 acc[4] = {};
  for (int kc = 0; kc < 512; kc += 64) {
    stage_tile_f32(As, Yf + (size_t)t0 * 512 + kc, 512, tid);
    stage_tile(Bs, Uod2T + (size_t)d0 * 512 + kc, 512, tid);
    __syncthreads();
    mma_strip(As, Bs, ms, lane, acc);
    __syncthreads();
  }
#pragma unroll
  for (int nt = 0; nt < 4; ++nt)
#pragma unroll
    for (int r = 0; r < 4; ++r)
      Os[(ms + lq + r) * 68 + nt * 16 + lm] = acc[nt][r];
  __syncthreads();
  for (int idx = tid; idx < 1024; idx += 256) {
    int r = idx >> 4, c4 = (idx & 15) << 2;
    *(float4*)&out[(size_t)(t0 + r) * D_ + d0 + c4] = *(const float4*)&Os[r * 68 + c4];
  }
}

// ================================================================ launch
extern "C" void kernel_launch(void* const* d_in, const int* in_sizes, int n_in,
                              void* d_out, int out_size, void* d_ws, size_t ws_size,
                              hipStream_t stream) {
  const float* x = (const float*)d_in[0];
  const float* Wg = (const float*)d_in[1];
  const float* uin_gate = (const float*)d_in[2];
  const float* core_gate = (const float*)d_in[3];
  const float* uout_gate = (const float*)d_in[4];
  const float* uin_up = (const float*)d_in[5];
  const float* core_up = (const float*)d_in[6];
  const float* uout_up = (const float*)d_in[7];
  const float* uin_down = (const float*)d_in[8];
  const float* core_down = (const float*)d_in[9];
  const float* uout_down = (const float*)d_in[10];
  float* out = (float*)d_out;

  char* ws = (char*)d_ws;
  size_t o = 0;
  auto alloc = [&](size_t bytes) { size_t r = o; o = (o + bytes + 255) & ~(size_t)255; return r; };
  size_t o_wsm = alloc(F_ * 4);
  size_t o_bucket = alloc((size_t)NEXP_ * 1024 * 4);            // 1 MB
  size_t o_cnt = alloc(NEXP_ * 4);
  size_t o_tickets = alloc(256);
  size_t o_off = alloc((NEXP_ + 1) * 4);
  size_t o_xb = alloc((size_t)T_ * D_ * 2);                     // 2 MB
  size_t o_uinT_g = alloc((size_t)G_ * 64 * 1024 * 2);          // 1 MB each
  size_t o_uinT_u = alloc((size_t)G_ * 64 * 1024 * 2);
  size_t o_uinT_d = alloc((size_t)G_ * 64 * 1024 * 2);
  size_t o_uoutT_g = alloc((size_t)G_ * 1024 * 64 * 2);
  size_t o_uoutT_u = alloc((size_t)G_ * 1024 * 64 * 2);
  size_t o_Uod2T = alloc((size_t)D_ * 512 * 2);                 // 1 MB
  size_t o_xgb = alloc((size_t)F_ * R_ * 2);                    // 1 MB
  size_t o_xub = alloc((size_t)F_ * R_ * 2);
  size_t o_Y = alloc((size_t)T_ * 512 * 4);                     // 2 MB fp32
  size_t o_pgp = alloc((size_t)PKZ_ * G_ * T_ * R_ * 4);        // 4 MB
  size_t o_pup = alloc((size_t)PKZ_ * G_ * T_ * R_ * 4);        // 4 MB
  size_t o_xdp = alloc((size_t)DKZ_ * F_ * R_ * 4);             // 8 MB
  (void)ws_size;

  float* wsm = (float*)(ws + o_wsm);
  int* bucket = (int*)(ws + o_bucket);
  int* cnt = (int*)(ws + o_cnt);
  int* tickets = (int*)(ws + o_tickets);
  int* off = (int*)(ws + o_off);
  unsigned short* xb = (unsigned short*)(ws + o_xb);
  unsigned short* uinT_g = (unsigned short*)(ws + o_uinT_g);
  unsigned short* uinT_u = (unsigned short*)(ws + o_uinT_u);
  unsigned short* uinT_d = (unsigned short*)(ws + o_uinT_d);
  unsigned short* uoutT_g = (unsigned short*)(ws + o_uoutT_g);
  unsigned short* uoutT_u = (unsigned short*)(ws + o_uoutT_u);
  unsigned short* Uod2T = (unsigned short*)(ws + o_Uod2T);
  unsigned short* xgb = (unsigned short*)(ws + o_xgb);
  unsigned short* xub = (unsigned short*)(ws + o_xub);
  float* Yf = (float*)(ws + o_Y);
  float* pgp = (float*)(ws + o_pgp);
  float* pup = (float*)(ws + o_pup);
  float* xdp = (float*)(ws + o_xdp);

  k_prep<<<896, 256, 0, stream>>>(x, uin_gate, uin_up, uin_down,
                                  uout_gate, uout_up, uout_down, xb,
                                  uinT_g, uinT_u, uinT_d,
                                  uoutT_g, uoutT_u, Uod2T, cnt, tickets, Yf);
  k_pre_router<<<768, 256, 0, stream>>>(x, Wg, xb, uinT_g, uinT_u,
                                        pgp, pup, wsm, bucket, cnt, tickets, off);
  k_core_gu<<<NEXP_ * 2, 256, 0, stream>>>(pgp, pup, core_gate, core_up, bucket, off, xgb, xub);
  k_fused_ad<<<dim3(16, G_, DKZ_), 256, 0, stream>>>(xgb, xub, uoutT_g, uoutT_u, uinT_d, off, xdp);
  k_down_core<<<NEXP_ * 2, 256, 0, stream>>>(xdp, core_down, bucket, wsm, off, Yf);
  k_fin<<<dim3(16, 16), 256, 0, stream>>>(Yf, Uod2T, out);
}

// Round 5
// 218.269 us; speedup vs baseline: 1.0977x; 1.0025x over previous
//
#include <hip/hip_runtime.h>
#include <hip/hip_bf16.h>
#include <math.h>

// Tucker MoE: T=1024, D=1024, DFF=1024, R=64, G=8, E=32, NEXP=256, K=8, F=8192
// Round 14: vectorize the router's Wg loads (r13's k_pre_router=60us was
// latency/issue-bound on 1024 scalar Wg dword loads per lane).
//  - lane now owns experts 4*lane..4*lane+3; per d one float4 Wg load
//    (coalesced, 256 VMEM inst/lane, 4x fewer). Per-expert fmaf order is
//    d-ascending over the wave's 256-chunk -> logits bit-identical to r13.
//  - partials stored as float4 to same part[w][t][e] layout; fold/topk/scan
//    code unchanged. Everything outside the router section unchanged.
// 6 dispatches:
//  D1 k_prep       : casts/transposes + cnt/tickets/Y zero
//  D2 k_pre_router : router+topk+scan (256 blk) || pre MFMA (512 blk)
//  D3 k_core_gu    : per-expert gate/up core (LDS, fp32) -> xgb/xub[p]
//  D4 k_fused_ad   : act(gate/up MFMA + silu*mul in LDS) fused w/ down MFMA
//  D5 k_down_core  : per-expert fold xdp + down core + wsm -> atomic Y fp32
//  D6 k_fin        : dense out = Y[1024,512] @ Uod2[512,1024] (bf16 MFMA)

#define T_ 1024
#define D_ 1024
#define DFF_ 1024
#define R_ 64
#define G_ 8
#define E_ 32
#define NEXP_ 256
#define K_ 8
#define F_ 8192
#define PKZ_ 2   // k_pre split-K
#define DKZ_ 4   // down split-K (chunks of 256 over DFF)
#define LP_ 72   // LDS tile pitch in bf16 elems (16B rows, 2-way bank alias = free)

typedef short bf16x8 __attribute__((ext_vector_type(8)));
typedef float f32x4 __attribute__((ext_vector_type(4)));

__device__ __forceinline__ unsigned short f2bf(float f) {
  unsigned int u = __float_as_uint(f);
  u += 0x7fffu + ((u >> 16) & 1u);  // RNE (finite inputs)
  return (unsigned short)(u >> 16);
}

__device__ __forceinline__ void stage_tile(short* dst, const unsigned short* src,
                                           int gp, int tid) {
  for (int idx = tid; idx < 512; idx += 256) {
    int r = idx >> 3, c8 = (idx & 7) << 3;
    *(uint4*)&dst[r * LP_ + c8] = *(const uint4*)&src[(size_t)r * gp + c8];
  }
}

__device__ __forceinline__ void stage_tile_guard(short* dst, const unsigned short* src,
                                                 int gp, int rows_valid, int tid) {
  for (int idx = tid; idx < 512; idx += 256) {
    int r = idx >> 3, c8 = (idx & 7) << 3;
    uint4 v = make_uint4(0u, 0u, 0u, 0u);
    if (r < rows_valid) v = *(const uint4*)&src[(size_t)r * gp + c8];
    *(uint4*)&dst[r * LP_ + c8] = v;
  }
}

// Stage a 64x64 bf16 tile from an fp32 source (convert on the fly).
__device__ __forceinline__ void stage_tile_f32(short* dst, const float* src,
                                               int gp, int tid) {
  for (int idx = tid; idx < 512; idx += 256) {
    int r = idx >> 3, c8 = (idx & 7) << 3;
    const float* s = &src[(size_t)r * gp + c8];
    float4 v0 = *(const float4*)s;
    float4 v1 = *(const float4*)(s + 4);
    uint4 u;
    u.x = ((unsigned)f2bf(v0.y) << 16) | f2bf(v0.x);
    u.y = ((unsigned)f2bf(v0.w) << 16) | f2bf(v0.z);
    u.z = ((unsigned)f2bf(v1.y) << 16) | f2bf(v1.x);
    u.w = ((unsigned)f2bf(v1.w) << 16) | f2bf(v1.z);
    *(uint4*)&dst[r * LP_ + c8] = u;
  }
}

// Wave computes a 16x64 strip (rows [ms,ms+16)) over K=64 from LDS tiles
// As (rows=m, k-contig) and Bs (rows=n, k-contig; i.e. B^T).
__device__ __forceinline__ void mma_strip(const short* As, const short* Bs,
                                          int ms, int lane, f32x4* acc) {
  int lm = lane & 15;
  int lk = (lane >> 4) << 3;
#pragma unroll
  for (int kc = 0; kc < 64; kc += 32) {
    bf16x8 a = *(const bf16x8*)&As[(ms + lm) * LP_ + kc + lk];
#pragma unroll
    for (int nt = 0; nt < 4; ++nt) {
      bf16x8 b = *(const bf16x8*)&Bs[(nt * 16 + lm) * LP_ + kc + lk];
      acc[nt] = __builtin_amdgcn_mfma_f32_16x16x32_bf16(a, b, acc[nt], 0, 0, 0);
    }
  }
}

// ---------------------------------------------------------------- D1: prep
// 896 blocks: id=b>>7: 0..4 cast+T, id 5 = uout_down -> Uod2T[d][g*64+r],
// id 6 = x cast + cnt/tickets zero + Y zero.
__global__ __launch_bounds__(256) void k_prep(
    const float* __restrict__ x,
    const float* __restrict__ s0, const float* __restrict__ s1,
    const float* __restrict__ s2, const float* __restrict__ s3,
    const float* __restrict__ s4, const float* __restrict__ s5,
    unsigned short* __restrict__ xb,
    unsigned short* __restrict__ d0, unsigned short* __restrict__ d1,
    unsigned short* __restrict__ d2, unsigned short* __restrict__ d3,
    unsigned short* __restrict__ d4, unsigned short* __restrict__ d5,
    int* __restrict__ cnt, int* __restrict__ tickets, float* __restrict__ Yf) {
  __shared__ float shbuf[64 * 65];
  int b = blockIdx.x;
  int id = b >> 7, rem = b & 127, g = rem >> 4, tile = rem & 15;
  if (id == 6) {
    size_t base = ((size_t)g * 16 + tile) * 8192;
    for (int i = threadIdx.x; i < 2048; i += 256) {
      size_t idx = base + (size_t)i * 4;
      float4 v = *(const float4*)&x[idx];
      xb[idx + 0] = f2bf(v.x);
      xb[idx + 1] = f2bf(v.y);
      xb[idx + 2] = f2bf(v.z);
      xb[idx + 3] = f2bf(v.w);
    }
    // zero Y: 128 blocks x 4096 floats = 1024x512
    size_t ybase = ((size_t)g * 16 + tile) * 4096;
    float4 z4 = make_float4(0.f, 0.f, 0.f, 0.f);
    for (int i = threadIdx.x; i < 1024; i += 256)
      *(float4*)&Yf[ybase + (size_t)i * 4] = z4;
    if (g == 0 && tile == 0) {
      cnt[threadIdx.x] = 0;
      if (threadIdx.x == 0) tickets[0] = 0;
    }
    return;
  }
  const float* src = id == 0 ? s0 : id == 1 ? s1 : id == 2 ? s2 : id == 3 ? s3 : id == 4 ? s4 : s5;
  unsigned short* dst = id == 0 ? d0 : id == 1 ? d1 : id == 2 ? d2 : id == 3 ? d3 : id == 4 ? d4 : d5;
  if (id < 3) {
    // uin*: src [g][1024][64] -> dst [g][64][1024]
    int r0 = tile * 64;
    for (int idx = threadIdx.x; idx < 4096; idx += 256) {
      int r = idx >> 6, c = idx & 63;
      shbuf[r * 65 + c] = src[((size_t)g * 1024 + r0 + r) * 64 + c];
    }
    __syncthreads();
    for (int idx = threadIdx.x; idx < 4096; idx += 256) {
      int c = idx >> 6, r = idx & 63;
      dst[((size_t)g * 64 + c) * 1024 + r0 + r] = f2bf(shbuf[r * 65 + c]);
    }
  } else {
    // uout*: src [g][64][1024]; id 3/4 -> [g][1024][64]; id 5 -> [d][g*64+r]
    int c0 = tile * 64;
    for (int idx = threadIdx.x; idx < 4096; idx += 256) {
      int r = idx >> 6, c = idx & 63;
      shbuf[r * 65 + c] = src[((size_t)g * 64 + r) * 1024 + c0 + c];
    }
    __syncthreads();
    if (id == 5) {
      for (int idx = threadIdx.x; idx < 4096; idx += 256) {
        int c = idx >> 6, r = idx & 63;
        dst[(size_t)(c0 + c) * 512 + g * 64 + r] = f2bf(shbuf[r * 65 + c]);
      }
    } else {
      for (int idx = threadIdx.x; idx < 4096; idx += 256) {
        int c = idx >> 6, r = idx & 63;
        dst[((size_t)g * 1024 + c0 + c) * 64 + r] = f2bf(shbuf[r * 65 + c]);
      }
    }
  }
}

// ---------------------------------------------------------------- D2: router+topk+scan || pre MFMA
// Grid 768: b<256 = router blocks (4 tokens each, split-K across the 4 waves,
// lane owns 4 consecutive experts -> float4 Wg loads; topk per wave; LAST
// router block scans cnt->off). b>=256 = 512 pre-MFMA blocks.
__global__ __launch_bounds__(256) void k_pre_router(
    const float* __restrict__ x, const float* __restrict__ Wg,
    const unsigned short* __restrict__ xb,
    const unsigned short* __restrict__ uinT_g, const unsigned short* __restrict__ uinT_u,
    float* __restrict__ Pgp, float* __restrict__ Pup,
    float* __restrict__ wsm, int* __restrict__ bucket, int* __restrict__ cnt,
    int* __restrict__ tickets, int* __restrict__ off) {
  __shared__ float smf[8192];  // 32 KB union: {xs[4][1024], part[4][4][256]} / MFMA tiles / scan
  __shared__ int lastfl;
  int b = blockIdx.x;
  int tid = threadIdx.x;
  if (b >= 256) {
    int b2 = b - 256;
    int tile = b2 & 15, g = (b2 >> 4) & 7, zz = b2 >> 7;
    int gu = zz >> 1, kz = zz & 1;
    const unsigned short* U = gu ? uinT_u : uinT_g;  // [G][64(r)][1024(d)]
    float* P = gu ? Pup : Pgp;
    int t0 = tile * 64;
    short* As = (short*)smf;
    short* Bs = (short*)smf + 64 * LP_;
    int lane = tid & 63, ms = (tid >> 6) * 16;
    f32x4 acc[4] = {};
    int dlo = kz * (D_ / PKZ_);
    for (int dc = dlo; dc < dlo + D_ / PKZ_; dc += 64) {
      stage_tile(As, xb + (size_t)t0 * D_ + dc, D_, tid);
      stage_tile(Bs, U + (size_t)g * 64 * 1024 + dc, 1024, tid);
      __syncthreads();
      mma_strip(As, Bs, ms, lane, acc);
      __syncthreads();
    }
    int lm = lane & 15, lq = (lane >> 4) * 4;
#pragma unroll
    for (int nt = 0; nt < 4; ++nt)
#pragma unroll
      for (int r = 0; r < 4; ++r)
        P[((size_t)(kz * G_ + g) * T_ + t0 + ms + lq + r) * R_ + nt * 16 + lm] = acc[nt][r];
    return;
  }
  // ---- router: 4 tokens/block; wave wv owns d-chunk [256wv, 256wv+256)
  // lane owns experts 4*lane..4*lane+3 (float4 Wg loads, coalesced)
  int t0 = b * 4;
  float* xs = smf;           // [4][1024]
  float* part = smf + 4096;  // [w][t][e] = [4][4][256]
  for (int i = tid; i < 1024; i += 256) {
    int j = i >> 8, d4 = (i & 255) << 2;
    *(float4*)&xs[j * 1024 + d4] = *(const float4*)&x[(size_t)(t0 + j) * D_ + d4];
  }
  __syncthreads();
  int wv = tid >> 6, lane = tid & 63;
  int dbase = wv * 256;
  int e4 = lane << 2;
  f32x4 ac0 = {}, ac1 = {}, ac2 = {}, ac3 = {};
#pragma unroll 2
  for (int d2 = 0; d2 < 256; d2 += 4) {
    int d = dbase + d2;
    f32x4 w0 = *(const f32x4*)&Wg[(size_t)(d + 0) * NEXP_ + e4];
    f32x4 w1 = *(const f32x4*)&Wg[(size_t)(d + 1) * NEXP_ + e4];
    f32x4 w2 = *(const f32x4*)&Wg[(size_t)(d + 2) * NEXP_ + e4];
    f32x4 w3 = *(const f32x4*)&Wg[(size_t)(d + 3) * NEXP_ + e4];
    float4 xv0 = *(const float4*)&xs[0 * 1024 + d];
    float4 xv1 = *(const float4*)&xs[1 * 1024 + d];
    float4 xv2 = *(const float4*)&xs[2 * 1024 + d];
    float4 xv3 = *(const float4*)&xs[3 * 1024 + d];
#pragma unroll
    for (int c = 0; c < 4; ++c) {
      float t0c = ac0[c], t1c = ac1[c], t2c = ac2[c], t3c = ac3[c];
      t0c = fmaf(xv0.x, w0[c], t0c);
      t0c = fmaf(xv0.y, w1[c], t0c);
      t0c = fmaf(xv0.z, w2[c], t0c);
      t0c = fmaf(xv0.w, w3[c], t0c);
      t1c = fmaf(xv1.x, w0[c], t1c);
      t1c = fmaf(xv1.y, w1[c], t1c);
      t1c = fmaf(xv1.z, w2[c], t1c);
      t1c = fmaf(xv1.w, w3[c], t1c);
      t2c = fmaf(xv2.x, w0[c], t2c);
      t2c = fmaf(xv2.y, w1[c], t2c);
      t2c = fmaf(xv2.z, w2[c], t2c);
      t2c = fmaf(xv2.w, w3[c], t2c);
      t3c = fmaf(xv3.x, w0[c], t3c);
      t3c = fmaf(xv3.y, w1[c], t3c);
      t3c = fmaf(xv3.z, w2[c], t3c);
      t3c = fmaf(xv3.w, w3[c], t3c);
      ac0[c] = t0c; ac1[c] = t1c; ac2[c] = t2c; ac3[c] = t3c;
    }
  }
  // store partials: float4 per token per lane -> part[wv][t][4*lane..]
  *(f32x4*)&part[(wv * 4 + 0) * 256 + e4] = ac0;
  *(f32x4*)&part[(wv * 4 + 1) * 256 + e4] = ac1;
  *(f32x4*)&part[(wv * 4 + 2) * 256 + e4] = ac2;
  *(f32x4*)&part[(wv * 4 + 3) * 256 + e4] = ac3;
  __syncthreads();
  // ---- wave wv folds + topk for token t0+wv (fold order w-ascending == r13)
  {
    int tt = wv;
    int t = t0 + tt;
    float v[4];
    int idx[4];
#pragma unroll
    for (int j2 = 0; j2 < 4; ++j2) {
      int e = lane + 64 * j2;
      idx[j2] = e;
      v[j2] = part[(0 * 4 + tt) * 256 + e] + part[(1 * 4 + tt) * 256 + e]
            + part[(2 * 4 + tt) * 256 + e] + part[(3 * 4 + tt) * 256 + e];
    }
    float topv[K_];
    int topi[K_];
#pragma unroll
    for (int k = 0; k < K_; ++k) {
      float bv = v[0];
      int bi = idx[0];
#pragma unroll
      for (int j2 = 1; j2 < 4; ++j2)
        if (v[j2] > bv || (v[j2] == bv && idx[j2] < bi)) { bv = v[j2]; bi = idx[j2]; }
#pragma unroll
      for (int o2 = 32; o2 > 0; o2 >>= 1) {
        float ov = __shfl_xor(bv, o2);
        int oi = __shfl_xor(bi, o2);
        if (ov > bv || (ov == bv && oi < bi)) { bv = ov; bi = oi; }
      }
      topv[k] = bv;
      topi[k] = bi;
#pragma unroll
      for (int j2 = 0; j2 < 4; ++j2)
        if (idx[j2] == bi) v[j2] = -INFINITY;
    }
    float m = topv[0];
    float ev[K_];
    float s = 0.f;
#pragma unroll
    for (int k = 0; k < K_; ++k) { ev[k] = expf(topv[k] - m); s += ev[k]; }
    float inv = 1.f / s;
    if (lane < K_) {
      wsm[t * K_ + lane] = ev[lane] * inv;
      int r1 = atomicAdd(&cnt[topi[lane]], 1);
      bucket[topi[lane] * 1024 + r1] = t * K_ + lane;
    }
  }
  // ---- last router block scans cnt -> off
  __threadfence();
  __syncthreads();
  if (tid == 0) lastfl = (atomicAdd(&tickets[0], 1) == 255) ? 1 : 0;
  __syncthreads();
  if (lastfl) {
    int* s = (int*)smf;
    int i = tid;
    int c0 = atomicAdd(&cnt[i], 0);  // coherent read of final counts
    s[i] = c0;
    __syncthreads();
    for (int d = 1; d < NEXP_; d <<= 1) {
      int vv = (i >= d) ? s[i - d] : 0;
      __syncthreads();
      s[i] += vv;
      __syncthreads();
    }
    off[i + 1] = s[i];
    if (i == 0) off[0] = 0;
  }
}

// ---------------------------------------------------------------- D3: per-expert gate/up core -> xgb/xub[p]
__global__ __launch_bounds__(256) void k_core_gu(const float* __restrict__ Pgp,
                                                 const float* __restrict__ Pup,
                                                 const float* __restrict__ core_g,
                                                 const float* __restrict__ core_u,
                                                 const int* __restrict__ bucket,
                                                 const int* __restrict__ off,
                                                 unsigned short* __restrict__ xgb,
                                                 unsigned short* __restrict__ xub) {
  int e = blockIdx.x >> 1, half = blockIdx.x & 1;
  int g = e >> 5;
  __shared__ float cg[4096], cu[4096];
  __shared__ float rg[4][64], ru[4][64];
  int tid = threadIdx.x;
  for (int i = tid; i < 1024; i += 256) {
    *(float4*)&cg[i * 4] = *(const float4*)&core_g[(size_t)e * 4096 + (size_t)i * 4];
    *(float4*)&cu[i * 4] = *(const float4*)&core_u[(size_t)e * 4096 + (size_t)i * 4];
  }
  int p0 = off[e], n = off[e + 1] - p0;
  int hn = (n + 1) >> 1;
  int i0 = half * hn;
  int i1 = i0 + hn; if (i1 > n) i1 = n;
  int pl = tid >> 6, o = tid & 63;
  __syncthreads();
  for (int ib = i0; ib < i1; ib += 4) {
    int i = ib + pl;
    bool valid = i < i1;
    int p = p0 + i;
    float sg = 0.f, su = 0.f;
    if (valid) {
      int t = bucket[e * 1024 + i] >> 3;
#pragma unroll
      for (int kz = 0; kz < PKZ_; ++kz) {
        sg += Pgp[((size_t)(kz * G_ + g) * T_ + t) * R_ + o];
        su += Pup[((size_t)(kz * G_ + g) * T_ + t) * R_ + o];
      }
    }
    __syncthreads();
    rg[pl][o] = sg;
    ru[pl][o] = su;
    __syncthreads();
    if (valid) {
      float ag = 0.f, au = 0.f;
#pragma unroll 8
      for (int r = 0; r < R_; ++r) {
        ag = fmaf(rg[pl][r], cg[r * R_ + o], ag);
        au = fmaf(ru[pl][r], cu[r * R_ + o], au);
      }
      xgb[(size_t)p * R_ + o] = f2bf(ag);
      xub[(size_t)p * R_ + o] = f2bf(au);
    }
  }
}

// ---------------------------------------------------------------- D4: fused act+down (MFMA)
__global__ __launch_bounds__(256) void k_fused_ad(const unsigned short* __restrict__ xgb,
                                                  const unsigned short* __restrict__ xub,
                                                  const unsigned short* __restrict__ uoutT_g,
                                                  const unsigned short* __restrict__ uoutT_u,
                                                  const unsigned short* __restrict__ uinT_d,
                                                  const int* __restrict__ off,
                                                  float* __restrict__ xdp) {
  int g = blockIdx.y;
  int kz = blockIdx.z;
  int p0 = off[g * E_];
  int pend = off[g * E_ + E_];
  int ntiles = (pend - p0 + 63) >> 6;
  __shared__ short Ag[64 * LP_], Au[64 * LP_];
  __shared__ short Bg[64 * LP_], Bu[64 * LP_], Bd[64 * LP_];
  __shared__ short Pt[64 * LP_];
  int tid = threadIdx.x, lane = tid & 63, ms = (tid >> 6) * 16;
  int lm = lane & 15, lq = (lane >> 4) * 4;
  for (int tile = blockIdx.x; tile < ntiles; tile += gridDim.x) {
    int pbase = p0 + tile * 64;
    int rv = pend - pbase; if (rv > 64) rv = 64;
    stage_tile_guard(Ag, xgb + (size_t)pbase * R_, R_, rv, tid);
    stage_tile_guard(Au, xub + (size_t)pbase * R_, R_, rv, tid);
    f32x4 accd[4] = {};
#pragma unroll
    for (int c4 = 0; c4 < 4; ++c4) {
      int cc = kz * (DFF_ / DKZ_) + c4 * 64;
      stage_tile(Bg, uoutT_g + ((size_t)g * DFF_ + cc) * R_, R_, tid);
      stage_tile(Bu, uoutT_u + ((size_t)g * DFF_ + cc) * R_, R_, tid);
      stage_tile(Bd, uinT_d + (size_t)g * 64 * 1024 + cc, 1024, tid);
      __syncthreads();
      f32x4 accg[4] = {}, accu[4] = {};
      mma_strip(Ag, Bg, ms, lane, accg);
      mma_strip(Au, Bu, ms, lane, accu);
#pragma unroll
      for (int nt = 0; nt < 4; ++nt)
#pragma unroll
        for (int r = 0; r < 4; ++r) {
          float gv = accg[nt][r];
          float av = gv / (1.f + expf(-gv)) * accu[nt][r];
          Pt[(ms + lq + r) * LP_ + nt * 16 + lm] = (short)f2bf(av);
        }
      mma_strip(Pt, Bd, ms, lane, accd);  // reads only own-wave rows of Pt
      __syncthreads();
    }
#pragma unroll
    for (int nt = 0; nt < 4; ++nt)
#pragma unroll
      for (int r = 0; r < 4; ++r) {
        int p = pbase + ms + lq + r;
        if (p < pend) xdp[((size_t)kz * F_ + p) * R_ + nt * 16 + lm] = accd[nt][r];
      }
    __syncthreads();
  }
}

// ---------------------------------------------------------------- D5: per-expert fold xdp + down core + wsm -> atomic Y
__global__ __launch_bounds__(256) void k_down_core(const float* __restrict__ xdp,
                                                   const float* __restrict__ core_d,
                                                   const int* __restrict__ bucket,
                                                   const float* __restrict__ wsm,
                                                   const int* __restrict__ off,
                                                   float* __restrict__ Yf) {
  int e = blockIdx.x >> 1, half = blockIdx.x & 1;
  int g = e >> 5;
  __shared__ float cd[4096];
  __shared__ float xs[4][64];
  int tid = threadIdx.x;
  for (int i = tid; i < 1024; i += 256)
    *(float4*)&cd[i * 4] = *(const float4*)&core_d[(size_t)e * 4096 + (size_t)i * 4];
  int p0 = off[e], n = off[e + 1] - p0;
  int hn = (n + 1) >> 1;
  int i0 = half * hn;
  int i1 = i0 + hn; if (i1 > n) i1 = n;
  int pl = tid >> 6, o = tid & 63;
  __syncthreads();
  for (int ib = i0; ib < i1; ib += 4) {
    int i = ib + pl;
    bool valid = i < i1;
    int p = p0 + i;
    int f = valid ? bucket[e * 1024 + i] : 0;
    float s = 0.f;
    if (valid) {
#pragma unroll
      for (int kz = 0; kz < DKZ_; ++kz) s += xdp[((size_t)kz * F_ + p) * R_ + o];
    }
    __syncthreads();
    xs[pl][o] = s;
    __syncthreads();
    if (valid) {
      float a = 0.f;
#pragma unroll 8
      for (int r = 0; r < R_; ++r) a = fmaf(xs[pl][r], cd[r * R_ + o], a);
      atomicAdd(&Yf[(size_t)(f >> 3) * 512 + g * 64 + o], wsm[f] * a);
    }
  }
}

// ---------------------------------------------------------------- D6: out = Y[1024,512] @ Uod2[512,1024], dense MFMA
__global__ __launch_bounds__(256) void k_fin(const float* __restrict__ Yf,
                                             const unsigned short* __restrict__ Uod2T,
                                             float* __restrict__ out) {
  int t0 = blockIdx.x * 64;
  int d0 = blockIdx.y * 64;
  __shared__ short As[64 * LP_], Bs[64 * LP_];
  __shared__ float Os[64 * 68];
  int tid = threadIdx.x, lane = tid & 63, ms = (tid >> 6) * 16;
  int lm = lane & 15, lq = (lane >> 4) * 4;
  f32x4 acc[4] = {};
  for (int kc = 0; kc < 512; kc += 64) {
    stage_tile_f32(As, Yf + (size_t)t0 * 512 + kc, 512, tid);
    stage_tile(Bs, Uod2T + (size_t)d0 * 512 + kc, 512, tid);
    __syncthreads();
    mma_strip(As, Bs, ms, lane, acc);
    __syncthreads();
  }
#pragma unroll
  for (int nt = 0; nt < 4; ++nt)
#pragma unroll
    for (int r = 0; r < 4; ++r)
      Os[(ms + lq + r) * 68 + nt * 16 + lm] = acc[nt][r];
  __syncthreads();
  for (int idx = tid; idx < 1024; idx += 256) {
    int r = idx >> 4, c4 = (idx & 15) << 2;
    *(float4*)&out[(size_t)(t0 + r) * D_ + d0 + c4] = *(const float4*)&Os[r * 68 + c4];
  }
}

// ================================================================ launch
extern "C" void kernel_launch(void* const* d_in, const int* in_sizes, int n_in,
                              void* d_out, int out_size, void* d_ws, size_t ws_size,
                              hipStream_t stream) {
  const float* x = (const float*)d_in[0];
  const float* Wg = (const float*)d_in[1];
  const float* uin_gate = (const float*)d_in[2];
  const float* core_gate = (const float*)d_in[3];
  const float* uout_gate = (const float*)d_in[4];
  const float* uin_up = (const float*)d_in[5];
  const float* core_up = (const float*)d_in[6];
  const float* uout_up = (const float*)d_in[7];
  const float* uin_down = (const float*)d_in[8];
  const float* core_down = (const float*)d_in[9];
  const float* uout_down = (const float*)d_in[10];
  float* out = (float*)d_out;

  char* ws = (char*)d_ws;
  size_t o = 0;
  auto alloc = [&](size_t bytes) { size_t r = o; o = (o + bytes + 255) & ~(size_t)255; return r; };
  size_t o_wsm = alloc(F_ * 4);
  size_t o_bucket = alloc((size_t)NEXP_ * 1024 * 4);            // 1 MB
  size_t o_cnt = alloc(NEXP_ * 4);
  size_t o_tickets = alloc(256);
  size_t o_off = alloc((NEXP_ + 1) * 4);
  size_t o_xb = alloc((size_t)T_ * D_ * 2);                     // 2 MB
  size_t o_uinT_g = alloc((size_t)G_ * 64 * 1024 * 2);          // 1 MB each
  size_t o_uinT_u = alloc((size_t)G_ * 64 * 1024 * 2);
  size_t o_uinT_d = alloc((size_t)G_ * 64 * 1024 * 2);
  size_t o_uoutT_g = alloc((size_t)G_ * 1024 * 64 * 2);
  size_t o_uoutT_u = alloc((size_t)G_ * 1024 * 64 * 2);
  size_t o_Uod2T = alloc((size_t)D_ * 512 * 2);                 // 1 MB
  size_t o_xgb = alloc((size_t)F_ * R_ * 2);                    // 1 MB
  size_t o_xub = alloc((size_t)F_ * R_ * 2);
  size_t o_Y = alloc((size_t)T_ * 512 * 4);                     // 2 MB fp32
  size_t o_pgp = alloc((size_t)PKZ_ * G_ * T_ * R_ * 4);        // 4 MB
  size_t o_pup = alloc((size_t)PKZ_ * G_ * T_ * R_ * 4);        // 4 MB
  size_t o_xdp = alloc((size_t)DKZ_ * F_ * R_ * 4);             // 8 MB
  (void)ws_size;

  float* wsm = (float*)(ws + o_wsm);
  int* bucket = (int*)(ws + o_bucket);
  int* cnt = (int*)(ws + o_cnt);
  int* tickets = (int*)(ws + o_tickets);
  int* off = (int*)(ws + o_off);
  unsigned short* xb = (unsigned short*)(ws + o_xb);
  unsigned short* uinT_g = (unsigned short*)(ws + o_uinT_g);
  unsigned short* uinT_u = (unsigned short*)(ws + o_uinT_u);
  unsigned short* uinT_d = (unsigned short*)(ws + o_uinT_d);
  unsigned short* uoutT_g = (unsigned short*)(ws + o_uoutT_g);
  unsigned short* uoutT_u = (unsigned short*)(ws + o_uoutT_u);
  unsigned short* Uod2T = (unsigned short*)(ws + o_Uod2T);
  unsigned short* xgb = (unsigned short*)(ws + o_xgb);
  unsigned short* xub = (unsigned short*)(ws + o_xub);
  float* Yf = (float*)(ws + o_Y);
  float* pgp = (float*)(ws + o_pgp);
  float* pup = (float*)(ws + o_pup);
  float* xdp = (float*)(ws + o_xdp);

  k_prep<<<896, 256, 0, stream>>>(x, uin_gate, uin_up, uin_down,
                                  uout_gate, uout_up, uout_down, xb,
                                  uinT_g, uinT_u, uinT_d,
                                  uoutT_g, uoutT_u, Uod2T, cnt, tickets, Yf);
  k_pre_router<<<768, 256, 0, stream>>>(x, Wg, xb, uinT_g, uinT_u,
                                        pgp, pup, wsm, bucket, cnt, tickets, off);
  k_core_gu<<<NEXP_ * 2, 256, 0, stream>>>(pgp, pup, core_gate, core_up, bucket, off, xgb, xub);
  k_fused_ad<<<dim3(16, G_, DKZ_), 256, 0, stream>>>(xgb, xub, uoutT_g, uoutT_u, uinT_d, off, xdp);
  k_down_core<<<NEXP_ * 2, 256, 0, stream>>>(xdp, core_down, bucket, wsm, off, Yf);
  k_fin<<<dim3(16, 16), 256, 0, stream>>>(Yf, Uod2T, out);
}